// Round 3
// baseline (233.382 us; speedup 1.0000x reference)
//
#include <hip/hip_runtime.h>
#include <math.h>

#define NB 32        // batches
#define NP 512       // N == M == 512
#define RG 8         // row-groups (blocks) per batch
#define RPB 64       // rows per block
#define ITERS 50
#define EPSV   0.05f
#define INVEPS 20.0f

typedef unsigned long long u64;
typedef unsigned int u32;

// ws layout: pack[2][NB][RG][NP] u32 (row-major: each 512-col stream is a
// contiguous single-writer array -> no false sharing), then epi[NB][RG] float2.
// Poison safety: 0xAAAAAAAA low 3 bits = 2; tag set {1,3,4,5,6,7} never
// contains 2 and all tags within a 6-window are distinct. epi tag 51.0f.
#define N_PACK (2*NB*RG*NP)
#define PAR_STRIDE (NB*RG*NP)      // 131072 u32 per parity buffer

// ---- agent-scope (device-coherent, LLC) primitives — cross-XCD safe ----
__device__ __forceinline__ void st32(u32* p, u32 v) {
  __hip_atomic_store(p, v, __ATOMIC_RELAXED, __HIP_MEMORY_SCOPE_AGENT);
}
__device__ __forceinline__ u32 ld32(const u32* p) {
  return __hip_atomic_load(p, __ATOMIC_RELAXED, __HIP_MEMORY_SCOPE_AGENT);
}
__device__ __forceinline__ void st64f(float2* p, float tag, float val) {
  union { float2 f; u64 u; } c; c.f = make_float2(tag, val);
  __hip_atomic_store((u64*)p, c.u, __ATOMIC_RELAXED, __HIP_MEMORY_SCOPE_AGENT);
}
__device__ __forceinline__ float2 ld64f(const float2* p) {
  union { u64 u; float2 f; } c;
  c.u = __hip_atomic_load((const u64*)p, __ATOMIC_RELAXED, __HIP_MEMORY_SCOPE_AGENT);
  return c.f;
}

// tag for iteration k: nibble LUT over k%6 -> {1,3,4,5,6,7}; all tags in any
// 6-window distinct, so tag(k) != tag(k-1) != tag(k-2) (stale detect exact)
__device__ __forceinline__ u32 tag_of(int k) {
  return (0x765431u >> (4 * (k % 6))) & 0xFu;
}
// pack fp32 value with tag in low 3 mantissa bits (<=7 ulp perturbation)
__device__ __forceinline__ u32 pack_slot(float v, u32 tag) {
  return (__float_as_uint(v) & ~7u) | tag;
}

// ---------------- single fused kernel: setup + 50 linear-Sinkhorn iters + ot ----
// ONE batch per 512-thread block, 64 rows each, RG=8 blocks/batch, grid=256
// (1 block/CU, all resident -> spin rendezvous deadlock-free).
//
// R3 = R2 resubmit (R2 bench was an infra failure, no kernel verdict) with
// defensive hardening: lower spin bails (1<<22) + s_sleep backoff in detect
// after 64 sweeps. Theory unchanged:
//
// The rendezvous was POLL-BANDWIDTH bound, not latency bound — 512-thread x
// 7-stream gang sweeps (~20/iter, from VALUBusy arithmetic) saturate
// whichever cache serves them (LLC in R0, per-XCD L2 in R1; that's why R1's
// remap cut FETCH 7x but not time). Fix: split detect from transfer.
//  - DETECT: wave 0 only, ONE global_load_dword per sweep (56 lanes sample
//    one element per producer-wave per remote stream: col 64w of stream r
//    at lane r*8+w). ~400x less poll traffic. Other waves park at barrier.
//  - TRANSFER: after detect, the baseline per-thread tagged pend-loop runs
//    once (rarely twice). Correctness rests ONLY on the tag protocol —
//    a stale/wrong sample can only cost an extra sweep, never accept stale.
//  - Single agent-scope publish; no dual store; no asm gang loads.
// XCD-local blockIdx decode kept (neutral for agent-scope traffic, free).
__global__ __launch_bounds__(NP) void emd_kernel(
    const float* __restrict__ a_mask, const float* __restrict__ pc_a,
    const float* __restrict__ b_mask, const float* __restrict__ pc_b,
    u32* __restrict__ pack, float2* __restrict__ epi,
    float* __restrict__ out)
{
  const int rb = blockIdx.x;
  // XCD-local decode: rb%8 = b%8 -> all 8 blocks of a batch on one XCD
  // under round-robin dispatch (confirmed by R1's FETCH collapse).
  const int xc = rb & 7;
  const int qq = rb >> 3;            // 0..31
  const int rg = qq >> 2;            // row-group 0..7
  const int b  = ((qq & 3) << 3) | xc;  // batch 0..31
  const int t  = threadIdx.x;
  const int chunk = t & 7;           // 8 threads per row
  const int lrow  = t >> 3;          // local row 0..63
  const int grow  = rg*RPB + lrow;
  const int lane  = t & 63, wid = t >> 6;

  __shared__ __align__(16) float rho_l[NP];   // exp(logv)
  __shared__ __align__(16) float bw_l[NP];    // col masses
  __shared__ __align__(16) float u_l[RPB];    // exp(logu)
  __shared__ __align__(16) float sm[NP];      // setup aw / epilogue scratch
  __shared__ float red[16];

  float4 eKreg[16];     // row slice: row=grow, cols 32*cc+4*chunk+e
  float  eKcol[RPB];    // col slice: col=t, rows rg*64+i
  float  aw_r, bw_t, hub = 0.f;

  // bulk-sweep base (baseline layout): stream r at base + r*NP, col t
  const u32* base0 = pack + (size_t)b*RG*NP + t;
  u32* ownp = pack + ((size_t)(b*RG + rg))*NP + t;

  // sample pointer for the wave-0 detect spin: lane = r*8 + w samples
  // remote stream RIDX(r), col 64*w (the first col of producer-wave w —
  // one sample per producer store instruction). Lanes >=56 are inert.
  #define RIDX(i) ((i) + ((i) >= rg ? 1 : 0))
  const int s_r = lane >> 3;         // 0..7 (only 0..6 used)
  const int s_w = lane & 7;          // producer wave sampled
  const int s_g = (s_r < 7) ? RIDX(s_r) : rg;
  const u32* smp0 = pack + ((size_t)b*RG + s_g)*NP + s_w*64;

  // ================= setup: masses, huber, expK caches =================
  {
    const float apt = a_mask[b*NP+t] * pc_a[((size_t)b*NP+t)*3+2];
    const float bpt = b_mask[b*NP+t] * pc_b[((size_t)b*NP+t)*3+2];
    float ra = apt, rv = bpt;
    #pragma unroll
    for (int o = 32; o; o >>= 1) { ra += __shfl_xor(ra, o); rv += __shfl_xor(rv, o); }
    if (lane == 0) { red[wid] = ra; red[8+wid] = rv; }
    __syncthreads();
    float asum = 0.f, bsum = 0.f;
    #pragma unroll
    for (int w = 0; w < 8; ++w) { asum += red[w]; bsum += red[8+w]; }
    const float e = asum - bsum, ae = fabsf(e);
    hub = (ae <= 1.f) ? 0.5f*e*e : (ae - 0.5f);
    sm[t]   = (apt > 0.f) ? apt/asum : 0.f;   // aw
    bw_l[t] = (bpt > 0.f) ? bpt/bsum : 0.f;
    __syncthreads();
    aw_r = sm[grow];
    bw_t = bw_l[t];
    const float ax = pc_a[((size_t)b*NP+grow)*3+0];
    const float ay = pc_a[((size_t)b*NP+grow)*3+1];
    const bool  va = aw_r > 0.f;
    #pragma unroll
    for (int cc = 0; cc < 16; ++cc) {
      float r[4];
      #pragma unroll
      for (int e2 = 0; e2 < 4; ++e2) {
        const int col = 32*cc + 4*chunk + e2;
        const float bx = pc_b[((size_t)b*NP+col)*3+0];
        const float by = pc_b[((size_t)b*NP+col)*3+1];
        const bool  vb = bw_l[col] > 0.f;
        const float dx = ax-bx, dy = ay-by;
        const float d  = sqrtf(dx*dx + dy*dy + 1e-12f);
        r[e2] = (va && vb) ? __expf((-INVEPS)*d) : 1.f;   // K=0 for masked pairs
      }
      eKreg[cc] = make_float4(r[0], r[1], r[2], r[3]);
    }
    const float bx0 = pc_b[((size_t)b*NP+t)*3+0];
    const float by0 = pc_b[((size_t)b*NP+t)*3+1];
    const bool  vb0 = bw_t > 0.f;
    #pragma unroll
    for (int i = 0; i < RPB; ++i) {
      const int row = rg*RPB + i;
      const float axi = pc_a[((size_t)b*NP+row)*3+0];  // wave-uniform -> scalar loads
      const float ayi = pc_a[((size_t)b*NP+row)*3+1];
      const bool  vai = sm[row] > 0.f;
      const float dx = axi-bx0, dy = ayi-by0;
      const float d  = sqrtf(dx*dx + dy*dy + 1e-12f);
      eKcol[i] = (vai && vb0) ? __expf((-INVEPS)*d) : 1.f;
    }
    rho_l[t] = 1.f;     // rho(0) = exp(logv=0) = 1
    __syncthreads();
  }

  // ================= main loop =================
  for (int k = 1; k <= ITERS; ++k) {
    const u32 tag = tag_of(k);
    const size_t po = (size_t)(k & 1) * (size_t)PAR_STRIDE;

    // ---- B: u(k) = aw / sum_j ek*rho(k-1)
    {
      const float4* r4p = (const float4*)rho_l;
      float dot = 0.f;
      #pragma unroll
      for (int cc = 0; cc < 16; ++cc) {
        const float4 g4 = r4p[8*cc + chunk];
        const float4 kk = eKreg[cc];
        dot += kk.x*g4.x + kk.y*g4.y + kk.z*g4.z + kk.w*g4.w;
      }
      #pragma unroll
      for (int o = 4; o; o >>= 1) dot += __shfl_xor(dot, o);   // 8-lane row reduce
      if (chunk == 0) u_l[lrow] = aw_r / fmaxf(dot, 1e-38f);
    }
    __syncthreads();   // u_l ready (also: all rho_l reads done)

    // ---- C: publish packed col partial s(k) for col t; keep own value local
    float sc_own;
    {
      const float4* u4p = (const float4*)u_l;
      float sc = 0.f;
      #pragma unroll
      for (int i4 = 0; i4 < 16; ++i4) {
        const float4 uu = u4p[i4];
        sc += eKcol[4*i4+0]*uu.x + eKcol[4*i4+1]*uu.y
            + eKcol[4*i4+2]*uu.z + eKcol[4*i4+3]*uu.w;
      }
      sc_own = sc;
      st32(ownp + po, pack_slot(sc, tag));   // single agent publish
    }

    // ---- DETECT: wave 0 sampled spin — 1 VMEM inst/sweep for the block.
    // All-fresh samples <=> every producer wave's store inst has (at least
    // partially) committed; any residue is caught by the tagged bulk below.
    if (wid == 0) {
      int sweeps = 0;
      while (true) {
        bool ok = true;
        if (lane < 56) ok = ((ld32(smp0 + po) & 7u) == tag);
        if (__all(ok)) break;
        ++sweeps;
        if (sweeps > 64) __builtin_amdgcn_s_sleep(1);   // gentle backoff
        if (sweeps > (1<<22)) break;    // fail visibly, never hang
      }
    }
    __syncthreads();   // waves 1-7 park here during the spin

    // ---- TRANSFER: tagged bulk sweep (typically exactly one pass)
    {
      u32 q[RG];
      #pragma unroll
      for (int r = 0; r < RG; ++r)
        if (r != rg) q[r] = ld32(base0 + po + (size_t)r*NP);
      unsigned pend = 0xFFu & ~(1u << rg);
      int sweeps = 0;
      while (true) {
        unsigned np = 0;
        #pragma unroll
        for (int r = 0; r < RG; ++r)
          if ((pend >> r) & 1u)
            if ((q[r] & 7u) != tag) np |= (1u << r);
        pend = np;
        if (!pend) break;
        #pragma unroll
        for (int r = 0; r < RG; ++r)
          if ((pend >> r) & 1u)
            q[r] = ld32(base0 + po + (size_t)r*NP);
        if (++sweeps > (1<<22)) break;   // fail visibly, never hang
      }
      float S = sc_own;
      #pragma unroll
      for (int r = 0; r < RG; ++r)
        if (r != rg) S += __uint_as_float(q[r]);   // <=7 ulp tag noise
      rho_l[t] = bw_t / fmaxf(S, 1e-38f);
    }
    __syncthreads();   // rho_l(k) ready for next B / epilogue
  }

  // ---- epilogue: ot partial = sum d^2 * u_i * ek * rho_j over my row slice
  float acc = 0.f;
  {
    const float ur = u_l[lrow];                  // u(50)
    const float4* r4p = (const float4*)rho_l;    // rho(50)
    #pragma unroll
    for (int cc = 0; cc < 16; ++cc) {
      const float4 g4 = r4p[8*cc + chunk];
      const float4 kk = eKreg[cc];
      const float ek[4] = {kk.x, kk.y, kk.z, kk.w};
      const float vv[4] = {g4.x, g4.y, g4.z, g4.w};
      #pragma unroll
      for (int e2 = 0; e2 < 4; ++e2) {
        const float lk = __logf(fmaxf(ek[e2], 1e-38f));  // d = -EPS*lk; masked: lk=0 -> d2=0
        const float d2 = (EPSV*lk)*(EPSV*lk);
        const float v  = d2 * ur * ek[e2] * vv[e2];
        acc += (ek[e2] > 0.f) ? v : 0.f;
      }
    }
  }
  // block-reduce, publish tagged epi, rg==0 gathers
  sm[t] = acc;
  __syncthreads();
  if (t < 64) {
    float v = 0.f;
    #pragma unroll
    for (int q = 0; q < 8; ++q) v += sm[t*8+q];
    #pragma unroll
    for (int o = 32; o; o >>= 1) v += __shfl_xor(v, o);
    if (t == 0) st64f(epi + (size_t)b*RG + rg, 51.f, v);
  }
  if (rg == 0 && t < RG) {     // gather: 8 lanes, poll + shfl-reduce
    float2 pr;
    long long spins = 0;
    do {
      pr = ld64f(epi + (size_t)b*RG + t);
      if (pr.x == 51.f) break;
      __builtin_amdgcn_s_sleep(1);
    } while (++spins < (1LL<<26));
    float v = pr.y;
    #pragma unroll
    for (int o = 4; o; o >>= 1) v += __shfl_xor(v, o);
    if (t == 0) out[b] = v + hub;
  }
}

extern "C" void kernel_launch(void* const* d_in, const int* in_sizes, int n_in,
                              void* d_out, int out_size, void* d_ws, size_t ws_size,
                              hipStream_t stream) {
  const float* a_mask = (const float*)d_in[0];
  const float* pc_a   = (const float*)d_in[1];
  const float* b_mask = (const float*)d_in[2];
  const float* pc_b   = (const float*)d_in[3];
  float* out = (float*)d_out;
  u32*    pack = (u32*)d_ws;                 // 1 MiB
  float2* epi  = (float2*)(pack + N_PACK);   // + 2 KiB
  (void)in_sizes; (void)n_in; (void)out_size; (void)ws_size;

  emd_kernel<<<NB*RG, NP, 0, stream>>>(a_mask, pc_a, b_mask, pc_b,
                                       pack, epi, out);
}

// Round 5
// 216.281 us; speedup vs baseline: 1.0791x; 1.0791x over previous
//
#include <hip/hip_runtime.h>
#include <math.h>

#define NB 32        // batches
#define NP 512       // N == M == 512
#define RG 8         // row-groups (blocks) per batch
#define RPB 64       // rows per block
#define ITERS 50
#define EPSV   0.05f
#define INVEPS 20.0f

typedef unsigned long long u64;
typedef unsigned int u32;

// ws layout: pack[2][NB][RG][NP] u32 (row-major: each 512-col stream is a
// contiguous single-writer array -> no false sharing), then epi[NB][RG] float2.
// Poison safety: 0xAAAAAAAA low 3 bits = 2; tag set {1,3,4,5,6,7} never
// contains 2 and all tags within a 6-window are distinct. epi tag 51.0f.
#define N_PACK (2*NB*RG*NP)
#define PAR_STRIDE (NB*RG*NP)      // 131072 u32 per parity buffer

// ---- agent-scope (device-coherent, LLC) primitives — cross-XCD safe ----
__device__ __forceinline__ void st32(u32* p, u32 v) {
  __hip_atomic_store(p, v, __ATOMIC_RELAXED, __HIP_MEMORY_SCOPE_AGENT);
}
__device__ __forceinline__ u32 ld32(const u32* p) {
  return __hip_atomic_load(p, __ATOMIC_RELAXED, __HIP_MEMORY_SCOPE_AGENT);
}
__device__ __forceinline__ void st64f(float2* p, float tag, float val) {
  union { float2 f; u64 u; } c; c.f = make_float2(tag, val);
  __hip_atomic_store((u64*)p, c.u, __ATOMIC_RELAXED, __HIP_MEMORY_SCOPE_AGENT);
}
__device__ __forceinline__ float2 ld64f(const float2* p) {
  union { u64 u; float2 f; } c;
  c.u = __hip_atomic_load((const u64*)p, __ATOMIC_RELAXED, __HIP_MEMORY_SCOPE_AGENT);
  return c.f;
}

// tag for iteration k: nibble LUT over k%6 -> {1,3,4,5,6,7}; all tags in any
// 6-window distinct, so tag(k) != tag(k-1) != tag(k-2) (stale detect exact)
__device__ __forceinline__ u32 tag_of(int k) {
  return (0x765431u >> (4 * (k % 6))) & 0xFu;
}
// pack fp32 value with tag in low 3 mantissa bits (<=7 ulp perturbation)
__device__ __forceinline__ u32 pack_slot(float v, u32 tag) {
  return (__float_as_uint(v) & ~7u) | tag;
}

// ---------------- single fused kernel: setup + 50 linear-Sinkhorn iters + ot ----
// ONE batch per 512-thread block, 64 rows each, RG=8 blocks/batch, grid=256
// (1 block/CU, all resident -> spin rendezvous deadlock-free).
//
// R5 = R0 (proven 153.7us; best measured) + ONE lever: 2-deep pipelined poll.
// Evidence log: R1 (L2-served polls, FETCH 95.6->14.0 MB) = no time win ->
// poll latency not critical. R3 (400x less poll traffic) = slower -> not
// congestion. R4 = unsafe (sc0 stale-L2 spin hazard), withdrawn. Remaining
// attackable term: poll SAMPLING period (= 1 LLC RT in R0, since the tag
// check waits the reloads). Two alternating in-flight generations (qa/qb)
// halve the sampling period; hipcc's counted vmcnt(N) waits only the older
// generation. Pure atomic loads: worst-case codegen degenerates to R0.
__global__ __launch_bounds__(NP) void emd_kernel(
    const float* __restrict__ a_mask, const float* __restrict__ pc_a,
    const float* __restrict__ b_mask, const float* __restrict__ pc_b,
    u32* __restrict__ pack, float2* __restrict__ epi,
    float* __restrict__ out)
{
  const int rb = blockIdx.x;
  const int b  = rb >> 3;            // batch (R0 decode: contiguous 8-block ranges)
  const int rg = rb & 7;             // row-group 0..7
  const int t  = threadIdx.x;
  const int chunk = t & 7;           // 8 threads per row
  const int lrow  = t >> 3;          // local row 0..63
  const int grow  = rg*RPB + lrow;
  const int lane  = t & 63, wid = t >> 6;

  __shared__ __align__(16) float rho_l[NP];   // exp(logv)
  __shared__ __align__(16) float bw_l[NP];    // col masses
  __shared__ __align__(16) float u_l[RPB];    // exp(logu)
  __shared__ __align__(16) float sm[NP];      // setup aw / epilogue scratch
  __shared__ float red[16];

  float4 eKreg[16];     // row slice: row=grow, cols 32*cc+4*chunk+e
  float  eKcol[RPB];    // col slice: col=t, rows rg*64+i
  float  aw_r, bw_t, hub = 0.f;

  // ================= setup: masses, huber, expK caches =================
  {
    const float apt = a_mask[b*NP+t] * pc_a[((size_t)b*NP+t)*3+2];
    const float bpt = b_mask[b*NP+t] * pc_b[((size_t)b*NP+t)*3+2];
    float ra = apt, rv = bpt;
    #pragma unroll
    for (int o = 32; o; o >>= 1) { ra += __shfl_xor(ra, o); rv += __shfl_xor(rv, o); }
    if (lane == 0) { red[wid] = ra; red[8+wid] = rv; }
    __syncthreads();
    float asum = 0.f, bsum = 0.f;
    #pragma unroll
    for (int w = 0; w < 8; ++w) { asum += red[w]; bsum += red[8+w]; }
    const float e = asum - bsum, ae = fabsf(e);
    hub = (ae <= 1.f) ? 0.5f*e*e : (ae - 0.5f);
    sm[t]   = (apt > 0.f) ? apt/asum : 0.f;   // aw
    bw_l[t] = (bpt > 0.f) ? bpt/bsum : 0.f;
    __syncthreads();
    aw_r = sm[grow];
    bw_t = bw_l[t];
    const float ax = pc_a[((size_t)b*NP+grow)*3+0];
    const float ay = pc_a[((size_t)b*NP+grow)*3+1];
    const bool  va = aw_r > 0.f;
    #pragma unroll
    for (int cc = 0; cc < 16; ++cc) {
      float r[4];
      #pragma unroll
      for (int e2 = 0; e2 < 4; ++e2) {
        const int col = 32*cc + 4*chunk + e2;
        const float bx = pc_b[((size_t)b*NP+col)*3+0];
        const float by = pc_b[((size_t)b*NP+col)*3+1];
        const bool  vb = bw_l[col] > 0.f;
        const float dx = ax-bx, dy = ay-by;
        const float d  = sqrtf(dx*dx + dy*dy + 1e-12f);
        r[e2] = (va && vb) ? __expf((-INVEPS)*d) : 1.f;   // K=0 for masked pairs
      }
      eKreg[cc] = make_float4(r[0], r[1], r[2], r[3]);
    }
    const float bx0 = pc_b[((size_t)b*NP+t)*3+0];
    const float by0 = pc_b[((size_t)b*NP+t)*3+1];
    const bool  vb0 = bw_t > 0.f;
    #pragma unroll
    for (int i = 0; i < RPB; ++i) {
      const int row = rg*RPB + i;
      const float axi = pc_a[((size_t)b*NP+row)*3+0];  // wave-uniform -> scalar loads
      const float ayi = pc_a[((size_t)b*NP+row)*3+1];
      const bool  vai = sm[row] > 0.f;
      const float dx = axi-bx0, dy = ayi-by0;
      const float d  = sqrtf(dx*dx + dy*dy + 1e-12f);
      eKcol[i] = (vai && vb0) ? __expf((-INVEPS)*d) : 1.f;
    }
    rho_l[t] = 1.f;     // rho(0) = exp(logv=0) = 1
    __syncthreads();
  }

  // ================= main loop =================
  for (int k = 1; k <= ITERS; ++k) {
    const u32 tag = tag_of(k);
    const int par = k & 1;
    const u32* base = pack + ((size_t)par*NB + b)*RG*NP + t;

    // ---- speculative early issue of the 7 remote streams for THIS iteration
    // (overlapped with B+C; peers that ran ahead are discovered for free;
    // tag(k)!=tag(k-2) makes stale detection exact)
    u32 qs[RG];
    #pragma unroll
    for (int r = 0; r < RG; ++r)
      if (r != rg) qs[r] = ld32(base + (size_t)r*NP);

    // ---- B: u(k) = aw / sum_j ek*rho(k-1)
    {
      const float4* r4p = (const float4*)rho_l;
      float dot = 0.f;
      #pragma unroll
      for (int cc = 0; cc < 16; ++cc) {
        const float4 g4 = r4p[8*cc + chunk];
        const float4 kk = eKreg[cc];
        dot += kk.x*g4.x + kk.y*g4.y + kk.z*g4.z + kk.w*g4.w;
      }
      #pragma unroll
      for (int o = 4; o; o >>= 1) dot += __shfl_xor(dot, o);   // 8-lane row reduce
      if (chunk == 0) u_l[lrow] = aw_r / fmaxf(dot, 1e-38f);
    }
    __syncthreads();   // u_l ready (also: all rho_l reads done)

    // ---- C: publish packed col partial s(k) for col t; keep own value local
    float sc_own;
    {
      const float4* u4p = (const float4*)u_l;
      float sc = 0.f;
      #pragma unroll
      for (int i4 = 0; i4 < 16; ++i4) {
        const float4 uu = u4p[i4];
        sc += eKcol[4*i4+0]*uu.x + eKcol[4*i4+1]*uu.y
            + eKcol[4*i4+2]*uu.z + eKcol[4*i4+3]*uu.w;
      }
      sc_own = sc;
      st32(pack + (((size_t)par*NB + b)*RG + rg)*NP + t, pack_slot(sc, tag));
    }

    // ---- A: 2-deep pipelined tagged poll. Generation A in flight while
    // generation B is checked and vice versa -> sampling period ~ RT/2.
    {
      u32 val[RG];
      unsigned pend = 0xFFu & ~(1u << rg);
      // consume speculative generation first (B+C time already elapsed)
      #pragma unroll
      for (int r = 0; r < RG; ++r)
        if (r != rg && ((qs[r] & 7u) == tag)) { val[r] = qs[r]; pend &= ~(1u << r); }
      if (pend) {
        u32 qa[RG], qb[RG];
        unsigned pa, pb;
        // prime generation A
        pa = pend;
        #pragma unroll
        for (int r = 0; r < RG; ++r)
          if ((pa >> r) & 1u) qa[r] = ld32(base + (size_t)r*NP);
        int sweeps = 0;
        while (true) {
          // issue generation B for everything still pending
          pb = pend;
          #pragma unroll
          for (int r = 0; r < RG; ++r)
            if ((pb >> r) & 1u) qb[r] = ld32(base + (size_t)r*NP);
          // consume generation A (compiler waits only qa's loads)
          #pragma unroll
          for (int r = 0; r < RG; ++r)
            if (((pa >> r) & 1u) && ((qa[r] & 7u) == tag)) {
              val[r] = qa[r]; pend &= ~(1u << r);
            }
          if (!pend) break;
          // issue generation A for everything still pending
          pa = pend;
          #pragma unroll
          for (int r = 0; r < RG; ++r)
            if ((pa >> r) & 1u) qa[r] = ld32(base + (size_t)r*NP);
          // consume generation B
          #pragma unroll
          for (int r = 0; r < RG; ++r)
            if (((pb >> r) & 1u) && ((qb[r] & 7u) == tag)) {
              val[r] = qb[r]; pend &= ~(1u << r);
            }
          if (!pend) break;
          if (++sweeps > (1<<22)) break;    // fail visibly, never hang
        }
      }
      float S = sc_own;
      #pragma unroll
      for (int r = 0; r < RG; ++r)
        if (r != rg) S += __uint_as_float(val[r]);   // <=7 ulp tag noise
      rho_l[t] = bw_t / fmaxf(S, 1e-38f);
    }
    __syncthreads();   // rho_l(k) ready for next B / epilogue
  }

  // ---- epilogue: ot partial = sum d^2 * u_i * ek * rho_j over my row slice
  float acc = 0.f;
  {
    const float ur = u_l[lrow];                  // u(50)
    const float4* r4p = (const float4*)rho_l;    // rho(50)
    #pragma unroll
    for (int cc = 0; cc < 16; ++cc) {
      const float4 g4 = r4p[8*cc + chunk];
      const float4 kk = eKreg[cc];
      const float ek[4] = {kk.x, kk.y, kk.z, kk.w};
      const float vv[4] = {g4.x, g4.y, g4.z, g4.w};
      #pragma unroll
      for (int e2 = 0; e2 < 4; ++e2) {
        const float lk = __logf(fmaxf(ek[e2], 1e-38f));  // d = -EPS*lk; masked: lk=0 -> d2=0
        const float d2 = (EPSV*lk)*(EPSV*lk);
        const float v  = d2 * ur * ek[e2] * vv[e2];
        acc += (ek[e2] > 0.f) ? v : 0.f;
      }
    }
  }
  // block-reduce, publish tagged epi, rg==0 gathers
  sm[t] = acc;
  __syncthreads();
  if (t < 64) {
    float v = 0.f;
    #pragma unroll
    for (int q = 0; q < 8; ++q) v += sm[t*8+q];
    #pragma unroll
    for (int o = 32; o; o >>= 1) v += __shfl_xor(v, o);
    if (t == 0) st64f(epi + (size_t)b*RG + rg, 51.f, v);
  }
  if (rg == 0 && t < RG) {     // gather: 8 lanes, poll + shfl-reduce
    float2 pr;
    long long spins = 0;
    do {
      pr = ld64f(epi + (size_t)b*RG + t);
      if (pr.x == 51.f) break;
      __builtin_amdgcn_s_sleep(1);
    } while (++spins < (1LL<<26));
    float v = pr.y;
    #pragma unroll
    for (int o = 4; o; o >>= 1) v += __shfl_xor(v, o);
    if (t == 0) out[b] = v + hub;
  }
}

extern "C" void kernel_launch(void* const* d_in, const int* in_sizes, int n_in,
                              void* d_out, int out_size, void* d_ws, size_t ws_size,
                              hipStream_t stream) {
  const float* a_mask = (const float*)d_in[0];
  const float* pc_a   = (const float*)d_in[1];
  const float* b_mask = (const float*)d_in[2];
  const float* pc_b   = (const float*)d_in[3];
  float* out = (float*)d_out;
  u32*    pack = (u32*)d_ws;                 // 1 MiB
  float2* epi  = (float2*)(pack + N_PACK);   // + 2 KiB
  (void)in_sizes; (void)n_in; (void)out_size; (void)ws_size;

  emd_kernel<<<NB*RG, NP, 0, stream>>>(a_mask, pc_a, b_mask, pc_b,
                                       pack, epi, out);
}